// Round 6
// baseline (429.178 us; speedup 1.0000x reference)
//
#include <hip/hip_runtime.h>
#include <hip/hip_bf16.h>
#include <math.h>
#include <type_traits>

typedef __bf16 bf16;
typedef __attribute__((ext_vector_type(8))) __bf16 bf16x8;
typedef __attribute__((ext_vector_type(4))) float f32x4;

#define MFMA16(a,b,c) __builtin_amdgcn_mfma_f32_16x16x32_bf16((a),(b),(c),0,0,0)

__device__ __forceinline__ void gload16(const void* gp, void* lp) {
  __builtin_amdgcn_global_load_lds(
      (const __attribute__((address_space(1))) void*)gp,
      (__attribute__((address_space(3))) void*)lp, 16, 0, 0);
}

// ---------------- transpose+cast: Wt[n][k] (bf16) = W[k][n] (fp32), up to 3 mats --------
__global__ __launch_bounds__(1024) void tr_cast(
    const float* __restrict__ w0, const float* __restrict__ w1,
    const float* __restrict__ w2, bf16* __restrict__ dst)
{
  __shared__ bf16 tile[64][65];
  const float* src = (blockIdx.z==0)?w0:(blockIdx.z==1)?w1:w2;
  bf16* d = dst + (size_t)blockIdx.z * (1024*1024);
  int x = threadIdx.x, y = threadIdx.y;
  int tc = blockIdx.x, tr = blockIdx.y;
  #pragma unroll
  for (int i=0;i<4;i++) {
    int r = y + i*16;
    tile[r][x] = (bf16)src[(size_t)(tr*64+r)*1024 + tc*64 + x];
  }
  __syncthreads();
  #pragma unroll
  for (int i=0;i<4;i++) {
    int r = y + i*16;
    d[(size_t)(tc*64+r)*1024 + tr*64 + x] = tile[x][r];
  }
}

// ---------------- fused QKV GEMM: [q|k|v] = x @ [WqT|WkT|WvT]^T + b, N=3072 ------------
// 128x128 tile, BK=32, 4 waves, 4x4 MFMA tiles/wave. Block-uniform output select.
__global__ __launch_bounds__(256) void gemm_qkv(
    const float* __restrict__ A, const bf16* __restrict__ Bt,
    const float* __restrict__ bq, const float* __restrict__ bk, const float* __restrict__ bv,
    bf16* __restrict__ q, bf16* __restrict__ k, bf16* __restrict__ v,
    int M, int K)
{
  __shared__ __align__(16) bf16 As[128*32];
  __shared__ __align__(16) bf16 Bs[128*32];
  const int tid  = threadIdx.x;
  const int wave = tid >> 6;
  const int lane = tid & 63;
  const int l15  = lane & 15;
  const int quad = lane >> 4;
  const int m0 = blockIdx.y * 128;
  const int n0 = blockIdx.x * 128;          // 0..2944; mat = n0>>10 (uniform: 8 blocks/matrix)
  const int wm = (wave >> 1) * 64;
  const int wn = (wave & 1) * 64;
  const int srow = lane >> 2;
  const int scol = (lane & 3) * 8;
  const int ar = tid >> 2;
  const int ac = (tid & 3) * 8;

  f32x4 acc[4][4];
  #pragma unroll
  for (int i=0;i<4;i++)
    #pragma unroll
    for (int j=0;j<4;j++)
      acc[i][j] = (f32x4){0.f,0.f,0.f,0.f};

  for (int k0 = 0; k0 < K; k0 += 32) {
    __syncthreads();
    #pragma unroll
    for (int p=0;p<2;p++) {
      int c = p*4 + wave;
      int row = c*16 + srow;
      gload16(Bt + (size_t)(n0+row)*K + k0 + scol, Bs + c*512);
    }
    {
      const float* ap0 = A + (size_t)(m0 + ar)*K + k0 + ac;
      const float* ap1 = ap0 + (size_t)64*K;
      f32x4 x0 = *(const f32x4*)(ap0);
      f32x4 x1 = *(const f32x4*)(ap0 + 4);
      f32x4 y0 = *(const f32x4*)(ap1);
      f32x4 y1 = *(const f32x4*)(ap1 + 4);
      bf16x8 a0, a1;
      #pragma unroll
      for (int j=0;j<4;j++) {
        a0[j] = (bf16)x0[j]; a0[4+j] = (bf16)x1[j];
        a1[j] = (bf16)y0[j]; a1[4+j] = (bf16)y1[j];
      }
      *(bf16x8*)(As + ar*32 + ac)        = a0;
      *(bf16x8*)(As + (ar + 64)*32 + ac) = a1;
    }
    __syncthreads();
    bf16x8 af[4], bfr[4];
    #pragma unroll
    for (int t=0;t<4;t++) {
      af[t]  = *(const bf16x8*)(As + (wm + t*16 + l15)*32 + quad*8);
      bfr[t] = *(const bf16x8*)(Bs + (wn + t*16 + l15)*32 + quad*8);
    }
    #pragma unroll
    for (int mt=0;mt<4;mt++)
      #pragma unroll
      for (int nt=0;nt<4;nt++)
        acc[mt][nt] = MFMA16(af[mt], bfr[nt], acc[mt][nt]);
  }

  const int mat = n0 >> 10;
  const float* bsel = (mat==0) ? bq : (mat==1) ? bk : bv;
  bf16*       osel  = (mat==0) ? q  : (mat==1) ? k  : v;
  #pragma unroll
  for (int nt=0;nt<4;nt++) {
    int col = n0 + wn + nt*16 + l15;
    int cw  = col & 1023;
    float bvv = bsel[cw];
    #pragma unroll
    for (int mt=0;mt<4;mt++) {
      int row = m0 + wm + mt*16 + quad*4;
      #pragma unroll
      for (int r=0;r<4;r++)
        osel[(size_t)(row + r)*1024 + cw] = (bf16)(acc[mt][nt][r] + bvv);
    }
  }
}

// ---------------- GEMM (single output): C[M][N] = A @ Bt^T + bias ----------------
template<typename TA, typename TC>
__global__ __launch_bounds__(256) void gemm_bias(
    const TA* __restrict__ A, const bf16* __restrict__ Bt,
    const float* __restrict__ bias, TC* __restrict__ C,
    int M, int N, int K)
{
  __shared__ __align__(16) bf16 As[128*32];
  __shared__ __align__(16) bf16 Bs[128*32];
  const int tid  = threadIdx.x;
  const int wave = tid >> 6;
  const int lane = tid & 63;
  const int l15  = lane & 15;
  const int quad = lane >> 4;
  const int m0 = blockIdx.y * 128;
  const int n0 = blockIdx.x * 128;
  const int wm = (wave >> 1) * 64;
  const int wn = (wave & 1) * 64;
  const int srow = lane >> 2;
  const int scol = (lane & 3) * 8;
  const int ar = tid >> 2;
  const int ac = (tid & 3) * 8;

  f32x4 acc[4][4];
  #pragma unroll
  for (int i=0;i<4;i++)
    #pragma unroll
    for (int j=0;j<4;j++)
      acc[i][j] = (f32x4){0.f,0.f,0.f,0.f};

  for (int k0 = 0; k0 < K; k0 += 32) {
    __syncthreads();
    #pragma unroll
    for (int p=0;p<2;p++) {
      int c = p*4 + wave;
      int row = c*16 + srow;
      gload16(Bt + (size_t)(n0+row)*K + k0 + scol, Bs + c*512);
    }
    if constexpr (std::is_same<TA, bf16>::value) {
      #pragma unroll
      for (int p=0;p<2;p++) {
        int c = p*4 + wave;
        int row = c*16 + srow;
        gload16(A + (size_t)(m0+row)*K + k0 + scol, As + c*512);
      }
    } else {
      const float* ap0 = (const float*)A + (size_t)(m0 + ar)*K + k0 + ac;
      const float* ap1 = ap0 + (size_t)64*K;
      f32x4 x0 = *(const f32x4*)(ap0);
      f32x4 x1 = *(const f32x4*)(ap0 + 4);
      f32x4 y0 = *(const f32x4*)(ap1);
      f32x4 y1 = *(const f32x4*)(ap1 + 4);
      bf16x8 a0, a1;
      #pragma unroll
      for (int j=0;j<4;j++) {
        a0[j] = (bf16)x0[j]; a0[4+j] = (bf16)x1[j];
        a1[j] = (bf16)y0[j]; a1[4+j] = (bf16)y1[j];
      }
      *(bf16x8*)(As + ar*32 + ac)        = a0;
      *(bf16x8*)(As + (ar + 64)*32 + ac) = a1;
    }
    __syncthreads();
    bf16x8 af[4], bfr[4];
    #pragma unroll
    for (int t=0;t<4;t++) {
      af[t]  = *(const bf16x8*)(As + (wm + t*16 + l15)*32 + quad*8);
      bfr[t] = *(const bf16x8*)(Bs + (wn + t*16 + l15)*32 + quad*8);
    }
    #pragma unroll
    for (int mt=0;mt<4;mt++)
      #pragma unroll
      for (int nt=0;nt<4;nt++)
        acc[mt][nt] = MFMA16(af[mt], bfr[nt], acc[mt][nt]);
  }

  #pragma unroll
  for (int nt=0;nt<4;nt++) {
    int col = n0 + wn + nt*16 + l15;
    float bvv = bias[col];
    #pragma unroll
    for (int mt=0;mt<4;mt++) {
      int row = m0 + wm + mt*16 + quad*4;
      #pragma unroll
      for (int r=0;r<4;r++)
        C[(size_t)(row + r)*N + col] = (TC)(acc[mt][nt][r] + bvv);
    }
  }
}

// ---------------- flash attention: causal, static-max softmax, 32 q-rows/wave ----------
// Grid: 1024 blocks = 32 q128-tiles (heavy/light interleaved) x 32 (b,h).
// Block: 256 thr = 4 waves; wave w covers q-rows [w*32, w*32+32) as 2 groups of 16.
// li computed by MFMA against a ones-fragment (no per-element adds, no final shuffle).
__global__ __launch_bounds__(256) void attn_fwd(
    const bf16* __restrict__ Q, const bf16* __restrict__ Kp,
    const bf16* __restrict__ V, bf16* __restrict__ O)
{
  __shared__ __align__(16) bf16 Ks[2*64*72];  // [buf][t][d] stride 72
  __shared__ __align__(16) bf16 Vt[2*64*72];  // [buf][d][t]
  __shared__ __align__(16) bf16 Ps[128*72];   // [qrow][t] — wave-private rows

  const int tid  = threadIdx.x;
  const int w    = tid >> 6;
  const int lane = tid & 63;
  const int l15  = lane & 15;
  const int quad = lane >> 4;

  const int bid = blockIdx.x;
  const int jj  = bid >> 5;                       // 0..31
  const int qt  = (jj & 1) ? (31 - (jj >> 1)) : (jj >> 1);  // interleave heavy/light
  const int bh  = bid & 31;
  const int h   = bh & 15;
  const int b   = bh >> 4;

  const size_t headoff = (size_t)h * 64;
  const size_t bbase   = (size_t)b * 4096;

  // Q fragments, 2 row-groups: A-layout m=l15, k=quad*8+j
  bf16x8 aq[2][2];
  #pragma unroll
  for (int g=0; g<2; g++) {
    int row = qt*128 + w*32 + g*16 + l15;
    const bf16* qp = Q + (bbase + row)*1024 + headoff + quad*8;
    aq[g][0] = *(const bf16x8*)(qp);
    aq[g][1] = *(const bf16x8*)(qp + 32);
  }

  bf16x8 ones;
  #pragma unroll
  for (int j=0;j<8;j++) ones[j] = (bf16)1.0f;

  f32x4 acco[2][4], accli[2];
  #pragma unroll
  for (int g=0; g<2; g++) {
    accli[g] = (f32x4){0.f,0.f,0.f,0.f};
    #pragma unroll
    for (int i=0;i<4;i++) acco[g][i] = (f32x4){0.f,0.f,0.f,0.f};
  }

  const int kt_row = tid >> 2;        // K staging: row t (0..63)
  const int kt_col = (tid & 3) * 16;  // 16-col slab

  // stage tile 0 -> buf 0
  {
    const bf16* kp = Kp + (bbase + kt_row)*1024 + headoff + kt_col;
    bf16x8 k0 = *(const bf16x8*)(kp);
    bf16x8 k1 = *(const bf16x8*)(kp + 8);
    *(bf16x8*)(Ks + kt_row*72 + kt_col)     = k0;
    *(bf16x8*)(Ks + kt_row*72 + kt_col + 8) = k1;
    const bf16* vp = V + (bbase + lane)*1024 + headoff + w*16;
    bf16x8 v0 = *(const bf16x8*)(vp);
    bf16x8 v1 = *(const bf16x8*)(vp + 8);
    #pragma unroll
    for (int j=0;j<8;j++) {
      Vt[(w*16 + j    )*72 + lane] = v0[j];
      Vt[(w*16 + 8 + j)*72 + lane] = v1[j];
    }
  }
  __syncthreads();

  const int ktmax = 2*qt + 1;   // last causal k-tile (inclusive)

  for (int kt = 0; kt <= ktmax; ++kt) {
    const int p = kt & 1;
    const bool pre = (kt < ktmax);     // block-uniform

    bf16x8 kr0, kr1, vr0, vr1;
    if (pre) {
      const bf16* kp = Kp + (bbase + (size_t)(kt+1)*64 + kt_row)*1024 + headoff + kt_col;
      kr0 = *(const bf16x8*)(kp);
      kr1 = *(const bf16x8*)(kp + 8);
      const bf16* vp = V + (bbase + (size_t)(kt+1)*64 + lane)*1024 + headoff + w*16;
      vr0 = *(const bf16x8*)(vp);
      vr1 = *(const bf16x8*)(vp + 8);
    }

    const bf16* ksb = Ks + p*4608;
    const bf16* vtb = Vt + p*4608;

    // S = Q K^T: 2 groups x 4 nt; B-frags shared across groups
    f32x4 accs[2][4];
    #pragma unroll
    for (int g=0; g<2; g++)
      #pragma unroll
      for (int i=0;i<4;i++) accs[g][i] = (f32x4){0.f,0.f,0.f,0.f};
    #pragma unroll
    for (int kk=0;kk<2;kk++) {
      bf16x8 bk[4];
      #pragma unroll
      for (int nt=0;nt<4;nt++)
        bk[nt] = *(const bf16x8*)(ksb + (nt*16 + l15)*72 + kk*32 + quad*8);
      #pragma unroll
      for (int g=0; g<2; g++)
        #pragma unroll
        for (int nt=0;nt<4;nt++)
          accs[g][nt] = MFMA16(aq[g][kk], bk[nt], accs[g][nt]);
    }

    // softmax: p = 2^(s*0.125*log2e), clamped; mask only on diagonal tiles
    const bool masked = (kt >= 2*qt);  // block-uniform: only last two tiles
    #pragma unroll
    for (int g=0; g<2; g++) {
      const int grow = qt*128 + w*32 + g*16 + quad*4;
      #pragma unroll
      for (int nt=0;nt<4;nt++) {
        const int gcol = kt*64 + nt*16 + l15;
        #pragma unroll
        for (int r=0;r<4;r++) {
          float t  = fminf(accs[g][nt][r] * 0.1803368801f, 86.0f);
          float pf = exp2f(t);
          if (masked) pf = (gcol <= grow + r) ? pf : 0.0f;
          Ps[(w*32 + g*16 + quad*4 + r)*72 + nt*16 + l15] = (bf16)pf;
        }
      }
    }

    // O += P @ V ; li += P @ ones  (Ps wave-private; DS ops in-order within wave)
    #pragma unroll
    for (int kk=0;kk<2;kk++) {
      bf16x8 bv[4];
      #pragma unroll
      for (int nt=0;nt<4;nt++)
        bv[nt] = *(const bf16x8*)(vtb + (nt*16 + l15)*72 + kk*32 + quad*8);
      #pragma unroll
      for (int g=0; g<2; g++) {
        bf16x8 ap = *(const bf16x8*)(Ps + (w*32 + g*16 + l15)*72 + kk*32 + quad*8);
        #pragma unroll
        for (int nt=0;nt<4;nt++)
          acco[g][nt] = MFMA16(ap, bv[nt], acco[g][nt]);
        accli[g] = MFMA16(ap, ones, accli[g]);
      }
    }

    if (pre) {
      bf16* ksn = Ks + (p^1)*4608;
      bf16* vtn = Vt + (p^1)*4608;
      *(bf16x8*)(ksn + kt_row*72 + kt_col)     = kr0;
      *(bf16x8*)(ksn + kt_row*72 + kt_col + 8) = kr1;
      #pragma unroll
      for (int j=0;j<8;j++) {
        vtn[(w*16 + j    )*72 + lane] = vr0[j];
        vtn[(w*16 + 8 + j)*72 + lane] = vr1[j];
      }
      __syncthreads();
    }
  }

  // normalize + store; accli[g][r] = li for row (g, quad*4+r) — identical across cols
  #pragma unroll
  for (int g=0; g<2; g++) {
    int rowb = qt*128 + w*32 + g*16 + quad*4;
    #pragma unroll
    for (int r=0;r<4;r++) {
      float inv = 1.0f / accli[g][r];
      #pragma unroll
      for (int nt=0;nt<4;nt++)
        O[(bbase + rowb + r)*1024 + headoff + nt*16 + l15] = (bf16)(acco[g][nt][r] * inv);
    }
  }
}

extern "C" void kernel_launch(void* const* d_in, const int* in_sizes, int n_in,
                              void* d_out, int out_size, void* d_ws, size_t ws_size,
                              hipStream_t stream) {
  const float* x  = (const float*)d_in[0];
  const float* Wq = (const float*)d_in[1];
  const float* bq = (const float*)d_in[2];
  const float* Wk = (const float*)d_in[3];
  const float* bk = (const float*)d_in[4];
  const float* Wv = (const float*)d_in[5];
  const float* bv = (const float*)d_in[6];
  const float* Wo = (const float*)d_in[7];
  const float* bo = (const float*)d_in[8];
  float* out = (float*)d_out;

  // ws (bf16 elems): q 8M | k 8M | v 8M | ao 8M = 64 MB.
  // WtQKV (3M) aliases ao (free until attn writes). WtO (1M) aliases q (free after attn).
  bf16* ws = (bf16*)d_ws;
  bf16* q  = ws;
  bf16* k  = q + (size_t)8192*1024;
  bf16* v  = k + (size_t)8192*1024;
  bf16* ao = v + (size_t)8192*1024;
  bf16* WtQKV = ao;
  bf16* WtO   = q;

  tr_cast<<<dim3(16,16,3), dim3(64,16), 0, stream>>>(Wq, Wk, Wv, WtQKV);
  gemm_qkv<<<dim3(24,64), 256, 0, stream>>>(x, WtQKV, bq, bk, bv, q, k, v, 8192, 1024);
  attn_fwd<<<1024, 256, 0, stream>>>(q, k, v, ao);
  tr_cast<<<dim3(16,16,1), dim3(64,16), 0, stream>>>(Wo, Wo, Wo, WtO);
  gemm_bias<bf16, float><<<dim3(8,64), 256, 0, stream>>>(ao, WtO, bo, out, 8192, 1024, 1024);
}

// Round 7
// 366.983 us; speedup vs baseline: 1.1695x; 1.1695x over previous
//
#include <hip/hip_runtime.h>
#include <hip/hip_bf16.h>
#include <math.h>
#include <type_traits>

typedef __bf16 bf16;
typedef __attribute__((ext_vector_type(8))) __bf16 bf16x8;
typedef __attribute__((ext_vector_type(4))) __bf16 bf16x4;
typedef __attribute__((ext_vector_type(4))) short short4v;
typedef __attribute__((ext_vector_type(4))) float f32x4;

#define MFMA16(a,b,c)  __builtin_amdgcn_mfma_f32_16x16x32_bf16((a),(b),(c),0,0,0)
#define MFMAK16(a,b,c) __builtin_amdgcn_mfma_f32_16x16x16bf16_1k((a),(b),(c),0,0,0)

__device__ __forceinline__ void gload16(const void* gp, void* lp) {
  __builtin_amdgcn_global_load_lds(
      (const __attribute__((address_space(1))) void*)gp,
      (__attribute__((address_space(3))) void*)lp, 16, 0, 0);
}

// ---------------- transpose+cast: Wt[n][k] (bf16) = W[k][n] (fp32), up to 3 mats --------
__global__ __launch_bounds__(1024) void tr_cast(
    const float* __restrict__ w0, const float* __restrict__ w1,
    const float* __restrict__ w2, bf16* __restrict__ dst)
{
  __shared__ bf16 tile[64][65];
  const float* src = (blockIdx.z==0)?w0:(blockIdx.z==1)?w1:w2;
  bf16* d = dst + (size_t)blockIdx.z * (1024*1024);
  int x = threadIdx.x, y = threadIdx.y;
  int tc = blockIdx.x, tr = blockIdx.y;
  #pragma unroll
  for (int i=0;i<4;i++) {
    int r = y + i*16;
    tile[r][x] = (bf16)src[(size_t)(tr*64+r)*1024 + tc*64 + x];
  }
  __syncthreads();
  #pragma unroll
  for (int i=0;i<4;i++) {
    int r = y + i*16;
    d[(size_t)(tc*64+r)*1024 + tr*64 + x] = tile[x][r];
  }
}

// ---------------- fused QKV GEMM: [q|k|v] = x @ [WqT|WkT|WvT]^T + b, N=3072 ------------
__global__ __launch_bounds__(256) void gemm_qkv(
    const float* __restrict__ A, const bf16* __restrict__ Bt,
    const float* __restrict__ bq, const float* __restrict__ bk, const float* __restrict__ bv,
    bf16* __restrict__ q, bf16* __restrict__ k, bf16* __restrict__ v,
    int M, int K)
{
  __shared__ __align__(16) bf16 As[128*32];
  __shared__ __align__(16) bf16 Bs[128*32];
  const int tid  = threadIdx.x;
  const int wave = tid >> 6;
  const int lane = tid & 63;
  const int l15  = lane & 15;
  const int quad = lane >> 4;
  const int m0 = blockIdx.y * 128;
  const int n0 = blockIdx.x * 128;
  const int wm = (wave >> 1) * 64;
  const int wn = (wave & 1) * 64;
  const int srow = lane >> 2;
  const int scol = (lane & 3) * 8;
  const int ar = tid >> 2;
  const int ac = (tid & 3) * 8;

  f32x4 acc[4][4];
  #pragma unroll
  for (int i=0;i<4;i++)
    #pragma unroll
    for (int j=0;j<4;j++)
      acc[i][j] = (f32x4){0.f,0.f,0.f,0.f};

  for (int k0 = 0; k0 < K; k0 += 32) {
    __syncthreads();
    #pragma unroll
    for (int p=0;p<2;p++) {
      int c = p*4 + wave;
      int row = c*16 + srow;
      gload16(Bt + (size_t)(n0+row)*K + k0 + scol, Bs + c*512);
    }
    {
      const float* ap0 = A + (size_t)(m0 + ar)*K + k0 + ac;
      const float* ap1 = ap0 + (size_t)64*K;
      f32x4 x0 = *(const f32x4*)(ap0);
      f32x4 x1 = *(const f32x4*)(ap0 + 4);
      f32x4 y0 = *(const f32x4*)(ap1);
      f32x4 y1 = *(const f32x4*)(ap1 + 4);
      bf16x8 a0, a1;
      #pragma unroll
      for (int j=0;j<4;j++) {
        a0[j] = (bf16)x0[j]; a0[4+j] = (bf16)x1[j];
        a1[j] = (bf16)y0[j]; a1[4+j] = (bf16)y1[j];
      }
      *(bf16x8*)(As + ar*32 + ac)        = a0;
      *(bf16x8*)(As + (ar + 64)*32 + ac) = a1;
    }
    __syncthreads();
    bf16x8 af[4], bfr[4];
    #pragma unroll
    for (int t=0;t<4;t++) {
      af[t]  = *(const bf16x8*)(As + (wm + t*16 + l15)*32 + quad*8);
      bfr[t] = *(const bf16x8*)(Bs + (wn + t*16 + l15)*32 + quad*8);
    }
    #pragma unroll
    for (int mt=0;mt<4;mt++)
      #pragma unroll
      for (int nt=0;nt<4;nt++)
        acc[mt][nt] = MFMA16(af[mt], bfr[nt], acc[mt][nt]);
  }

  const int mat = n0 >> 10;
  const float* bsel = (mat==0) ? bq : (mat==1) ? bk : bv;
  bf16*       osel  = (mat==0) ? q  : (mat==1) ? k  : v;
  #pragma unroll
  for (int nt=0;nt<4;nt++) {
    int col = n0 + wn + nt*16 + l15;
    int cw  = col & 1023;
    float bvv = bsel[cw];
    #pragma unroll
    for (int mt=0;mt<4;mt++) {
      int row = m0 + wm + mt*16 + quad*4;
      #pragma unroll
      for (int r=0;r<4;r++)
        osel[(size_t)(row + r)*1024 + cw] = (bf16)(acc[mt][nt][r] + bvv);
    }
  }
}

// ---------------- GEMM (single output): C[M][N] = A @ Bt^T + bias ----------------
template<typename TA, typename TC>
__global__ __launch_bounds__(256) void gemm_bias(
    const TA* __restrict__ A, const bf16* __restrict__ Bt,
    const float* __restrict__ bias, TC* __restrict__ C,
    int M, int N, int K)
{
  __shared__ __align__(16) bf16 As[128*32];
  __shared__ __align__(16) bf16 Bs[128*32];
  const int tid  = threadIdx.x;
  const int wave = tid >> 6;
  const int lane = tid & 63;
  const int l15  = lane & 15;
  const int quad = lane >> 4;
  const int m0 = blockIdx.y * 128;
  const int n0 = blockIdx.x * 128;
  const int wm = (wave >> 1) * 64;
  const int wn = (wave & 1) * 64;
  const int srow = lane >> 2;
  const int scol = (lane & 3) * 8;
  const int ar = tid >> 2;
  const int ac = (tid & 3) * 8;

  f32x4 acc[4][4];
  #pragma unroll
  for (int i=0;i<4;i++)
    #pragma unroll
    for (int j=0;j<4;j++)
      acc[i][j] = (f32x4){0.f,0.f,0.f,0.f};

  for (int k0 = 0; k0 < K; k0 += 32) {
    __syncthreads();
    #pragma unroll
    for (int p=0;p<2;p++) {
      int c = p*4 + wave;
      int row = c*16 + srow;
      gload16(Bt + (size_t)(n0+row)*K + k0 + scol, Bs + c*512);
    }
    if constexpr (std::is_same<TA, bf16>::value) {
      #pragma unroll
      for (int p=0;p<2;p++) {
        int c = p*4 + wave;
        int row = c*16 + srow;
        gload16(A + (size_t)(m0+row)*K + k0 + scol, As + c*512);
      }
    } else {
      const float* ap0 = (const float*)A + (size_t)(m0 + ar)*K + k0 + ac;
      const float* ap1 = ap0 + (size_t)64*K;
      f32x4 x0 = *(const f32x4*)(ap0);
      f32x4 x1 = *(const f32x4*)(ap0 + 4);
      f32x4 y0 = *(const f32x4*)(ap1);
      f32x4 y1 = *(const f32x4*)(ap1 + 4);
      bf16x8 a0, a1;
      #pragma unroll
      for (int j=0;j<4;j++) {
        a0[j] = (bf16)x0[j]; a0[4+j] = (bf16)x1[j];
        a1[j] = (bf16)y0[j]; a1[4+j] = (bf16)y1[j];
      }
      *(bf16x8*)(As + ar*32 + ac)        = a0;
      *(bf16x8*)(As + (ar + 64)*32 + ac) = a1;
    }
    __syncthreads();
    bf16x8 af[4], bfr[4];
    #pragma unroll
    for (int t=0;t<4;t++) {
      af[t]  = *(const bf16x8*)(As + (wm + t*16 + l15)*32 + quad*8);
      bfr[t] = *(const bf16x8*)(Bs + (wn + t*16 + l15)*32 + quad*8);
    }
    #pragma unroll
    for (int mt=0;mt<4;mt++)
      #pragma unroll
      for (int nt=0;nt<4;nt++)
        acc[mt][nt] = MFMA16(af[mt], bfr[nt], acc[mt][nt]);
  }

  #pragma unroll
  for (int nt=0;nt<4;nt++) {
    int col = n0 + wn + nt*16 + l15;
    float bvv = bias[col];
    #pragma unroll
    for (int mt=0;mt<4;mt++) {
      int row = m0 + wm + mt*16 + quad*4;
      #pragma unroll
      for (int r=0;r<4;r++)
        C[(size_t)(row + r)*N + col] = (TC)(acc[mt][nt][r] + bvv);
    }
  }
}

// ---------------- flash attention, S^T formulation: P never leaves registers ----------
// St = K·Q^T via 16x16x32 (A=K, B=Q). St C-layout (col=l15=q, row=quad*4+r=t) IS the
// B-operand layout of 16x16x16 MFMA (k=quad*4+j) -> PV runs as O^T = V^T·Pt with
// A=V^T from Vt[d][t] (b64 reads), B=Pt straight from softmax registers. li via a
// ones-A MFMA. No Ps array: LDS 36 KB -> 4 blocks/CU.
// Grid: 2048 = qt(64, descending) x (b,h)(32). Block: 256 = 4 waves x 16 q-rows.
__global__ __launch_bounds__(256, 4) void attn_fwd(
    const bf16* __restrict__ Q, const bf16* __restrict__ Kp,
    const bf16* __restrict__ V, bf16* __restrict__ O)
{
  __shared__ __align__(16) bf16 Ks[2*64*72];  // [buf][t][d] stride 72
  __shared__ __align__(16) bf16 Vt[2*64*72];  // [buf][d][t] stride 72

  const int tid  = threadIdx.x;
  const int w    = tid >> 6;
  const int lane = tid & 63;
  const int l15  = lane & 15;
  const int quad = lane >> 4;

  const int bid = blockIdx.x;
  const int qt  = 63 - (bid >> 5);   // descending work order
  const int bh  = bid & 31;
  const int h   = bh & 15;
  const int b   = bh >> 4;

  const size_t headoff = (size_t)h * 64;
  const size_t bbase   = (size_t)b * 4096;

  // Q fragments (B-operand for St): n=l15=q, k=quad*8+j=d
  bf16x8 aq[2];
  {
    int row = qt*64 + w*16 + l15;
    const bf16* qp = Q + (bbase + row)*1024 + headoff + quad*8;
    aq[0] = *(const bf16x8*)(qp);
    aq[1] = *(const bf16x8*)(qp + 32);
  }

  short4v ones_s;
  {
    bf16x4 o1;
    #pragma unroll
    for (int j=0;j<4;j++) o1[j] = (bf16)1.0f;
    ones_s = __builtin_bit_cast(short4v, o1);
  }

  f32x4 acco[4];   // O^T tiles: [nt: d-chunk], C-layout col=q, row=d
  f32x4 accli;     // li[q] in every reg
  #pragma unroll
  for (int i=0;i<4;i++) acco[i] = (f32x4){0.f,0.f,0.f,0.f};
  accli = (f32x4){0.f,0.f,0.f,0.f};

  const int kt_row = tid >> 2;        // K staging: row t (0..63)
  const int kt_col = (tid & 3) * 16;  // 16-col slab

  // stage tile 0 -> buf 0
  {
    const bf16* kp = Kp + (bbase + kt_row)*1024 + headoff + kt_col;
    bf16x8 k0 = *(const bf16x8*)(kp);
    bf16x8 k1 = *(const bf16x8*)(kp + 8);
    *(bf16x8*)(Ks + kt_row*72 + kt_col)     = k0;
    *(bf16x8*)(Ks + kt_row*72 + kt_col + 8) = k1;
    const bf16* vp = V + (bbase + lane)*1024 + headoff + w*16;
    bf16x8 v0 = *(const bf16x8*)(vp);
    bf16x8 v1 = *(const bf16x8*)(vp + 8);
    #pragma unroll
    for (int j=0;j<8;j++) {
      Vt[(w*16 + j    )*72 + lane] = v0[j];
      Vt[(w*16 + 8 + j)*72 + lane] = v1[j];
    }
  }
  __syncthreads();

  for (int kt = 0; kt <= qt; ++kt) {
    const int p = kt & 1;
    const bool pre = (kt < qt);      // block-uniform

    bf16x8 kr0, kr1, vr0, vr1;
    if (pre) {
      const bf16* kp = Kp + (bbase + (size_t)(kt+1)*64 + kt_row)*1024 + headoff + kt_col;
      kr0 = *(const bf16x8*)(kp);
      kr1 = *(const bf16x8*)(kp + 8);
      const bf16* vp = V + (bbase + (size_t)(kt+1)*64 + lane)*1024 + headoff + w*16;
      vr0 = *(const bf16x8*)(vp);
      vr1 = *(const bf16x8*)(vp + 8);
    }

    const bf16* ksb = Ks + p*4608;
    const bf16* vtb = Vt + p*4608;

    // St = K·Q^T: 4 tt-tiles (t) x 16 q. A=K rows (m=t), B=Q rows (n=q).
    f32x4 accs[4];
    #pragma unroll
    for (int i=0;i<4;i++) accs[i] = (f32x4){0.f,0.f,0.f,0.f};
    #pragma unroll
    for (int kk=0;kk<2;kk++) {
      #pragma unroll
      for (int tt=0;tt<4;tt++) {
        bf16x8 ka = *(const bf16x8*)(ksb + (tt*16 + l15)*72 + kk*32 + quad*8);
        accs[tt] = MFMA16(ka, aq[kk], accs[tt]);
      }
    }

    // softmax: p = 2^(s*log2e/8), clamp; mask only the diagonal tile. Pt stays in regs.
    const bool diag = (kt == qt);    // block-uniform
    short4v pts[4];
    #pragma unroll
    for (int tt=0;tt<4;tt++) {
      bf16x4 pb;
      #pragma unroll
      for (int r=0;r<4;r++) {
        float tv = fminf(accs[tt][r] * 0.1803368801f, 60.0f);
        float pf = exp2f(tv);
        if (diag && (tt*16 + quad*4 + r > w*16 + l15)) pf = 0.0f;
        pb[r] = (bf16)pf;
      }
      pts[tt] = __builtin_bit_cast(short4v, pb);
    }

    // O^T += V^T·Pt  (16x16x16: A=V^T[d][t] b64 reads, B=Pt from regs)
    #pragma unroll
    for (int nt=0;nt<4;nt++) {
      #pragma unroll
      for (int tt=0;tt<4;tt++) {
        bf16x4 va = *(const bf16x4*)(vtb + (nt*16 + l15)*72 + tt*16 + quad*4);
        acco[nt] = MFMAK16(__builtin_bit_cast(short4v, va), pts[tt], acco[nt]);
      }
    }
    // li += ones·Pt
    #pragma unroll
    for (int tt=0;tt<4;tt++)
      accli = MFMAK16(ones_s, pts[tt], accli);

    if (pre) {
      bf16* ksn = Ks + (p^1)*4608;
      bf16* vtn = Vt + (p^1)*4608;
      *(bf16x8*)(ksn + kt_row*72 + kt_col)     = kr0;
      *(bf16x8*)(ksn + kt_row*72 + kt_col + 8) = kr1;
      #pragma unroll
      for (int j=0;j<8;j++) {
        vtn[(w*16 + j    )*72 + lane] = vr0[j];
        vtn[(w*16 + 8 + j)*72 + lane] = vr1[j];
      }
      __syncthreads();
    }
  }

  // epilogue: lane holds O^T[d=nt*16+quad*4+r][q=l15]; divide by li[q]=accli[0], store
  {
    float inv = 1.0f / accli[0];
    int qrow = qt*64 + w*16 + l15;
    bf16* ob = O + (bbase + qrow)*1024 + headoff;
    #pragma unroll
    for (int nt=0;nt<4;nt++) {
      bf16x4 o;
      #pragma unroll
      for (int r=0;r<4;r++) o[r] = (bf16)(acco[nt][r] * inv);
      *(bf16x4*)(ob + nt*16 + quad*4) = o;
    }
  }
}

extern "C" void kernel_launch(void* const* d_in, const int* in_sizes, int n_in,
                              void* d_out, int out_size, void* d_ws, size_t ws_size,
                              hipStream_t stream) {
  const float* x  = (const float*)d_in[0];
  const float* Wq = (const float*)d_in[1];
  const float* bq = (const float*)d_in[2];
  const float* Wk = (const float*)d_in[3];
  const float* bk = (const float*)d_in[4];
  const float* Wv = (const float*)d_in[5];
  const float* bv = (const float*)d_in[6];
  const float* Wo = (const float*)d_in[7];
  const float* bo = (const float*)d_in[8];
  float* out = (float*)d_out;

  // ws (bf16 elems): q 8M | k 8M | v 8M | ao 8M = 64 MB.
  // WtQKV (3M) aliases ao (free until attn writes). WtO (1M) aliases q (free after attn).
  bf16* ws = (bf16*)d_ws;
  bf16* q  = ws;
  bf16* k  = q + (size_t)8192*1024;
  bf16* v  = k + (size_t)8192*1024;
  bf16* ao = v + (size_t)8192*1024;
  bf16* WtQKV = ao;
  bf16* WtO   = q;

  tr_cast<<<dim3(16,16,3), dim3(64,16), 0, stream>>>(Wq, Wk, Wv, WtQKV);
  gemm_qkv<<<dim3(24,64), 256, 0, stream>>>(x, WtQKV, bq, bk, bv, q, k, v, 8192, 1024);
  attn_fwd<<<2048, 256, 0, stream>>>(q, k, v, ao);
  tr_cast<<<dim3(16,16,1), dim3(64,16), 0, stream>>>(Wo, Wo, Wo, WtO);
  gemm_bias<bf16, float><<<dim3(8,64), 256, 0, stream>>>(ao, WtO, bo, out, 8192, 1024, 1024);
}

// Round 8
// 356.549 us; speedup vs baseline: 1.2037x; 1.0293x over previous
//
#include <hip/hip_runtime.h>
#include <hip/hip_bf16.h>
#include <math.h>

typedef __bf16 bf16;
typedef __attribute__((ext_vector_type(8))) __bf16 bf16x8;
typedef __attribute__((ext_vector_type(4))) __bf16 bf16x4;
typedef __attribute__((ext_vector_type(4))) short short4v;
typedef __attribute__((ext_vector_type(4))) float f32x4;

#define MFMA16(a,b,c)  __builtin_amdgcn_mfma_f32_16x16x32_bf16((a),(b),(c),0,0,0)
#define MFMAK16(a,b,c) __builtin_amdgcn_mfma_f32_16x16x16bf16_1k((a),(b),(c),0,0,0)

__device__ __forceinline__ void gload16(const void* gp, void* lp) {
  __builtin_amdgcn_global_load_lds(
      (const __attribute__((address_space(1))) void*)gp,
      (__attribute__((address_space(3))) void*)lp, 16, 0, 0);
}

// ---------------- x cast: fp32 -> bf16, 8 elems/thread ----------------
__global__ __launch_bounds__(256) void cast_x(
    const float* __restrict__ x, bf16* __restrict__ xb)
{
  size_t i = ((size_t)blockIdx.x*256 + threadIdx.x) * 8;
  f32x4 a = *(const f32x4*)(x+i);
  f32x4 b = *(const f32x4*)(x+i+4);
  bf16x8 o;
  #pragma unroll
  for (int j=0;j<4;j++) { o[j] = (bf16)a[j]; o[4+j] = (bf16)b[j]; }
  *(bf16x8*)(xb+i) = o;
}

// ---------------- transpose+cast: Wt[n][k] (bf16) = W[k][n] (fp32), up to 3 mats --------
__global__ __launch_bounds__(1024) void tr_cast(
    const float* __restrict__ w0, const float* __restrict__ w1,
    const float* __restrict__ w2, bf16* __restrict__ dst)
{
  __shared__ bf16 tile[64][65];
  const float* src = (blockIdx.z==0)?w0:(blockIdx.z==1)?w1:w2;
  bf16* d = dst + (size_t)blockIdx.z * (1024*1024);
  int x = threadIdx.x, y = threadIdx.y;
  int tc = blockIdx.x, tr = blockIdx.y;
  #pragma unroll
  for (int i=0;i<4;i++) {
    int r = y + i*16;
    tile[r][x] = (bf16)src[(size_t)(tr*64+r)*1024 + tc*64 + x];
  }
  __syncthreads();
  #pragma unroll
  for (int i=0;i<4;i++) {
    int r = y + i*16;
    d[(size_t)(tc*64+r)*1024 + tr*64 + x] = tile[x][r];
  }
}

// ---------------- fused QKV GEMM, pure gload16 staging (m97 path) ----------------
// [q|k|v] = xb @ [WqT|WkT|WvT]^T + b.  A bf16, Bt bf16, N=3072.
__global__ __launch_bounds__(256) void gemm_qkv(
    const bf16* __restrict__ A, const bf16* __restrict__ Bt,
    const float* __restrict__ bq, const float* __restrict__ bk, const float* __restrict__ bv,
    bf16* __restrict__ q, bf16* __restrict__ k, bf16* __restrict__ v,
    int M, int K)
{
  __shared__ __align__(16) bf16 As[128*32];
  __shared__ __align__(16) bf16 Bs[128*32];
  const int tid  = threadIdx.x;
  const int wave = tid >> 6;
  const int lane = tid & 63;
  const int l15  = lane & 15;
  const int quad = lane >> 4;
  const int m0 = blockIdx.y * 128;
  const int n0 = blockIdx.x * 128;
  const int wm = (wave >> 1) * 64;
  const int wn = (wave & 1) * 64;
  const int srow = lane >> 2;
  const int scol = (lane & 3) * 8;

  f32x4 acc[4][4];
  #pragma unroll
  for (int i=0;i<4;i++)
    #pragma unroll
    for (int j=0;j<4;j++)
      acc[i][j] = (f32x4){0.f,0.f,0.f,0.f};

  for (int k0 = 0; k0 < K; k0 += 32) {
    __syncthreads();
    #pragma unroll
    for (int p=0;p<2;p++) {
      int c = p*4 + wave;
      int row = c*16 + srow;
      gload16(A  + (size_t)(m0+row)*K + k0 + scol, As + c*512);
      gload16(Bt + (size_t)(n0+row)*K + k0 + scol, Bs + c*512);
    }
    __syncthreads();
    bf16x8 af[4], bfr[4];
    #pragma unroll
    for (int t=0;t<4;t++) {
      af[t]  = *(const bf16x8*)(As + (wm + t*16 + l15)*32 + quad*8);
      bfr[t] = *(const bf16x8*)(Bs + (wn + t*16 + l15)*32 + quad*8);
    }
    #pragma unroll
    for (int mt=0;mt<4;mt++)
      #pragma unroll
      for (int nt=0;nt<4;nt++)
        acc[mt][nt] = MFMA16(af[mt], bfr[nt], acc[mt][nt]);
  }

  const int mat = n0 >> 10;
  const float* bsel = (mat==0) ? bq : (mat==1) ? bk : bv;
  bf16*       osel  = (mat==0) ? q  : (mat==1) ? k  : v;
  #pragma unroll
  for (int nt=0;nt<4;nt++) {
    int col = n0 + wn + nt*16 + l15;
    int cw  = col & 1023;
    float bvv = bsel[cw];
    #pragma unroll
    for (int mt=0;mt<4;mt++) {
      int row = m0 + wm + mt*16 + quad*4;
      #pragma unroll
      for (int r=0;r<4;r++)
        osel[(size_t)(row + r)*1024 + cw] = (bf16)(acc[mt][nt][r] + bvv);
    }
  }
}

// ---------------- final GEMM: out(fp32) = ao(bf16) @ WtO^T + bo ----------------
__global__ __launch_bounds__(256) void gemm_out(
    const bf16* __restrict__ A, const bf16* __restrict__ Bt,
    const float* __restrict__ bias, float* __restrict__ C,
    int M, int N, int K)
{
  __shared__ __align__(16) bf16 As[128*32];
  __shared__ __align__(16) bf16 Bs[128*32];
  const int tid  = threadIdx.x;
  const int wave = tid >> 6;
  const int lane = tid & 63;
  const int l15  = lane & 15;
  const int quad = lane >> 4;
  const int m0 = blockIdx.y * 128;
  const int n0 = blockIdx.x * 128;
  const int wm = (wave >> 1) * 64;
  const int wn = (wave & 1) * 64;
  const int srow = lane >> 2;
  const int scol = (lane & 3) * 8;

  f32x4 acc[4][4];
  #pragma unroll
  for (int i=0;i<4;i++)
    #pragma unroll
    for (int j=0;j<4;j++)
      acc[i][j] = (f32x4){0.f,0.f,0.f,0.f};

  for (int k0 = 0; k0 < K; k0 += 32) {
    __syncthreads();
    #pragma unroll
    for (int p=0;p<2;p++) {
      int c = p*4 + wave;
      int row = c*16 + srow;
      gload16(A  + (size_t)(m0+row)*K + k0 + scol, As + c*512);
      gload16(Bt + (size_t)(n0+row)*K + k0 + scol, Bs + c*512);
    }
    __syncthreads();
    bf16x8 af[4], bfr[4];
    #pragma unroll
    for (int t=0;t<4;t++) {
      af[t]  = *(const bf16x8*)(As + (wm + t*16 + l15)*32 + quad*8);
      bfr[t] = *(const bf16x8*)(Bs + (wn + t*16 + l15)*32 + quad*8);
    }
    #pragma unroll
    for (int mt=0;mt<4;mt++)
      #pragma unroll
      for (int nt=0;nt<4;nt++)
        acc[mt][nt] = MFMA16(af[mt], bfr[nt], acc[mt][nt]);
  }

  #pragma unroll
  for (int nt=0;nt<4;nt++) {
    int col = n0 + wn + nt*16 + l15;
    float bvv = bias[col];
    #pragma unroll
    for (int mt=0;mt<4;mt++) {
      int row = m0 + wm + mt*16 + quad*4;
      #pragma unroll
      for (int r=0;r<4;r++)
        C[(size_t)(row + r)*N + col] = acc[mt][nt][r] + bvv;
    }
  }
}

// ---------------- flash attention, S^T formulation (unchanged from r7) ----------------
// O may alias Q: each (b,row,h-slice) is read-at-start / written-at-end by exactly
// one block, so in-place is race-free.
__global__ __launch_bounds__(256, 4) void attn_fwd(
    const bf16* __restrict__ Q, const bf16* __restrict__ Kp,
    const bf16* __restrict__ V, bf16* __restrict__ O)
{
  __shared__ __align__(16) bf16 Ks[2*64*72];  // [buf][t][d] stride 72
  __shared__ __align__(16) bf16 Vt[2*64*72];  // [buf][d][t] stride 72

  const int tid  = threadIdx.x;
  const int w    = tid >> 6;
  const int lane = tid & 63;
  const int l15  = lane & 15;
  const int quad = lane >> 4;

  const int bid = blockIdx.x;
  const int qt  = 63 - (bid >> 5);   // descending work order
  const int bh  = bid & 31;
  const int h   = bh & 15;
  const int b   = bh >> 4;

  const size_t headoff = (size_t)h * 64;
  const size_t bbase   = (size_t)b * 4096;

  bf16x8 aq[2];
  {
    int row = qt*64 + w*16 + l15;
    const bf16* qp = Q + (bbase + row)*1024 + headoff + quad*8;
    aq[0] = *(const bf16x8*)(qp);
    aq[1] = *(const bf16x8*)(qp + 32);
  }

  short4v ones_s;
  {
    bf16x4 o1;
    #pragma unroll
    for (int j=0;j<4;j++) o1[j] = (bf16)1.0f;
    ones_s = __builtin_bit_cast(short4v, o1);
  }

  f32x4 acco[4];
  f32x4 accli;
  #pragma unroll
  for (int i=0;i<4;i++) acco[i] = (f32x4){0.f,0.f,0.f,0.f};
  accli = (f32x4){0.f,0.f,0.f,0.f};

  const int kt_row = tid >> 2;
  const int kt_col = (tid & 3) * 16;

  {
    const bf16* kp = Kp + (bbase + kt_row)*1024 + headoff + kt_col;
    bf16x8 k0 = *(const bf16x8*)(kp);
    bf16x8 k1 = *(const bf16x8*)(kp + 8);
    *(bf16x8*)(Ks + kt_row*72 + kt_col)     = k0;
    *(bf16x8*)(Ks + kt_row*72 + kt_col + 8) = k1;
    const bf16* vp = V + (bbase + lane)*1024 + headoff + w*16;
    bf16x8 v0 = *(const bf16x8*)(vp);
    bf16x8 v1 = *(const bf16x8*)(vp + 8);
    #pragma unroll
    for (int j=0;j<8;j++) {
      Vt[(w*16 + j    )*72 + lane] = v0[j];
      Vt[(w*16 + 8 + j)*72 + lane] = v1[j];
    }
  }
  __syncthreads();

  for (int kt = 0; kt <= qt; ++kt) {
    const int p = kt & 1;
    const bool pre = (kt < qt);

    bf16x8 kr0, kr1, vr0, vr1;
    if (pre) {
      const bf16* kp = Kp + (bbase + (size_t)(kt+1)*64 + kt_row)*1024 + headoff + kt_col;
      kr0 = *(const bf16x8*)(kp);
      kr1 = *(const bf16x8*)(kp + 8);
      const bf16* vp = V + (bbase + (size_t)(kt+1)*64 + lane)*1024 + headoff + w*16;
      vr0 = *(const bf16x8*)(vp);
      vr1 = *(const bf16x8*)(vp + 8);
    }

    const bf16* ksb = Ks + p*4608;
    const bf16* vtb = Vt + p*4608;

    f32x4 accs[4];
    #pragma unroll
    for (int i=0;i<4;i++) accs[i] = (f32x4){0.f,0.f,0.f,0.f};
    #pragma unroll
    for (int kk=0;kk<2;kk++) {
      #pragma unroll
      for (int tt=0;tt<4;tt++) {
        bf16x8 ka = *(const bf16x8*)(ksb + (tt*16 + l15)*72 + kk*32 + quad*8);
        accs[tt] = MFMA16(ka, aq[kk], accs[tt]);
      }
    }

    const bool diag = (kt == qt);
    short4v pts[4];
    #pragma unroll
    for (int tt=0;tt<4;tt++) {
      bf16x4 pb;
      #pragma unroll
      for (int r=0;r<4;r++) {
        float tv = fminf(accs[tt][r] * 0.1803368801f, 60.0f);
        float pf = exp2f(tv);
        if (diag && (tt*16 + quad*4 + r > w*16 + l15)) pf = 0.0f;
        pb[r] = (bf16)pf;
      }
      pts[tt] = __builtin_bit_cast(short4v, pb);
    }

    #pragma unroll
    for (int nt=0;nt<4;nt++) {
      #pragma unroll
      for (int tt=0;tt<4;tt++) {
        bf16x4 va = *(const bf16x4*)(vtb + (nt*16 + l15)*72 + tt*16 + quad*4);
        acco[nt] = MFMAK16(__builtin_bit_cast(short4v, va), pts[tt], acco[nt]);
      }
    }
    #pragma unroll
    for (int tt=0;tt<4;tt++)
      accli = MFMAK16(ones_s, pts[tt], accli);

    if (pre) {
      bf16* ksn = Ks + (p^1)*4608;
      bf16* vtn = Vt + (p^1)*4608;
      *(bf16x8*)(ksn + kt_row*72 + kt_col)     = kr0;
      *(bf16x8*)(ksn + kt_row*72 + kt_col + 8) = kr1;
      #pragma unroll
      for (int j=0;j<8;j++) {
        vtn[(w*16 + j    )*72 + lane] = vr0[j];
        vtn[(w*16 + 8 + j)*72 + lane] = vr1[j];
      }
      __syncthreads();
    }
  }

  {
    float inv = 1.0f / accli[0];
    int qrow = qt*64 + w*16 + l15;
    bf16* ob = O + (bbase + qrow)*1024 + headoff;
    #pragma unroll
    for (int nt=0;nt<4;nt++) {
      bf16x4 o;
      #pragma unroll
      for (int r=0;r<4;r++) o[r] = (bf16)(acco[nt][r] * inv);
      *(bf16x4*)(ob + nt*16 + quad*4) = o;
    }
  }
}

extern "C" void kernel_launch(void* const* d_in, const int* in_sizes, int n_in,
                              void* d_out, int out_size, void* d_ws, size_t ws_size,
                              hipStream_t stream) {
  const float* x  = (const float*)d_in[0];
  const float* Wq = (const float*)d_in[1];
  const float* bq = (const float*)d_in[2];
  const float* Wk = (const float*)d_in[3];
  const float* bk = (const float*)d_in[4];
  const float* Wv = (const float*)d_in[5];
  const float* bv = (const float*)d_in[6];
  const float* Wo = (const float*)d_in[7];
  const float* bo = (const float*)d_in[8];
  float* out = (float*)d_out;

  // ws (bf16 elems, 64 MB): q 8M | k 8M | v 8M | xb 8M.
  // ao written in-place over q (block-exclusive slices). WtO reuses xb after gemm_qkv.
  // WtQKV (3M el) lives in d_out scratch (fully overwritten by the final GEMM).
  bf16* ws = (bf16*)d_ws;
  bf16* q  = ws;
  bf16* k  = q + (size_t)8192*1024;
  bf16* v  = k + (size_t)8192*1024;
  bf16* xb = v + (size_t)8192*1024;
  bf16* ao = q;                      // in-place
  bf16* WtQKV = (bf16*)d_out;        // scratch: dead before gemm_out writes d_out
  bf16* WtO   = xb;                  // xb dead after gemm_qkv

  tr_cast<<<dim3(16,16,3), dim3(64,16), 0, stream>>>(Wq, Wk, Wv, WtQKV);
  cast_x<<<4096, 256, 0, stream>>>(x, xb);
  gemm_qkv<<<dim3(24,64), 256, 0, stream>>>(xb, WtQKV, bq, bk, bv, q, k, v, 8192, 1024);
  tr_cast<<<dim3(16,16,1), dim3(64,16), 0, stream>>>(Wo, Wo, Wo, WtO);
  attn_fwd<<<2048, 256, 0, stream>>>(q, k, v, ao);
  gemm_out<<<dim3(8,64), 256, 0, stream>>>(ao, WtO, bo, out, 8192, 1024, 1024);
}